// Round 1
// baseline (2838.844 us; speedup 1.0000x reference)
//
#include <hip/hip_runtime.h>
#include <math.h>

// Problem constants (match reference)
constexpr int NN = 50000;    // nodes
constexpr int NE = 800000;   // undirected edges E0
constexpr int KS = 10;       // iterations
constexpr float LAM = 3.0f;  // lambda

// ---------------- precompute kernels ----------------

__global__ __launch_bounds__(256) void count_kernel(
    const int* __restrict__ src, const int* __restrict__ dst,
    int* __restrict__ cA, int* __restrict__ cR, int* __restrict__ cC) {
  int e = blockIdx.x * 256 + threadIdx.x;
  if (e >= NE) return;
  int s = src[e], d = dst[e];
  atomicAdd(&cA[s], 1);
  atomicAdd(&cA[d], 1);
  int r = s > d ? s : d;
  int c = s > d ? d : s;
  atomicAdd(&cR[r], 1);
  atomicAdd(&cC[c], 1);
}

__global__ __launch_bounds__(256) void dis_kernel(
    const int* __restrict__ cA, float* __restrict__ dis) {
  int i = blockIdx.x * 256 + threadIdx.x;
  if (i < NN) dis[i] = 1.0f / sqrtf((float)(cA[i] + 1)); // deg incl. self loop
}

// one block per array: exclusive scan of counts -> ptr (N+1) and cursor copy
__global__ __launch_bounds__(1024) void scan3_kernel(
    const int* __restrict__ cA, const int* __restrict__ cR, const int* __restrict__ cC,
    int* __restrict__ pA, int* __restrict__ pR, int* __restrict__ pC,
    int* __restrict__ uA, int* __restrict__ uR, int* __restrict__ uC) {
  const int* cnt; int* ptr; int* cur;
  if (blockIdx.x == 0)      { cnt = cA; ptr = pA; cur = uA; }
  else if (blockIdx.x == 1) { cnt = cR; ptr = pR; cur = uR; }
  else                      { cnt = cC; ptr = pC; cur = uC; }
  __shared__ int part[1024];
  int t = threadIdx.x;
  const int per = (NN + 1023) / 1024;  // 49
  int s0 = t * per;
  int s1 = s0 + per; if (s1 > NN) s1 = NN;
  if (s0 > NN) s0 = NN;
  int s = 0;
  for (int i = s0; i < s1; ++i) s += cnt[i];
  part[t] = s;
  __syncthreads();
  for (int off = 1; off < 1024; off <<= 1) {
    int v = part[t];
    int a = (t >= off) ? part[t - off] : 0;
    __syncthreads();
    part[t] = v + a;
    __syncthreads();
  }
  int base = (t == 0) ? 0 : part[t - 1];
  for (int i = s0; i < s1; ++i) {
    int cv = cnt[i];
    ptr[i] = base;
    cur[i] = base;
    base += cv;
  }
  if (s1 == NN) ptr[NN] = base;  // all trailing threads write the same total
}

__global__ __launch_bounds__(256) void scatter_kernel(
    const int* __restrict__ src, const int* __restrict__ dst,
    int* __restrict__ uA, int* __restrict__ uR, int* __restrict__ uC,
    int* __restrict__ adjc, int* __restrict__ reid, int* __restrict__ ceid) {
  int e = blockIdx.x * 256 + threadIdx.x;
  if (e >= NE) return;
  int s = src[e], d = dst[e];
  int p = atomicAdd(&uA[s], 1); adjc[p] = d;
  p = atomicAdd(&uA[d], 1);     adjc[p] = s;
  int r = s > d ? s : d;
  int c = s > d ? d : s;
  p = atomicAdd(&uR[r], 1);     reid[p] = e;
  p = atomicAdd(&uC[c], 1);     ceid[p] = e;
}

// ---------------- per-step kernels ----------------
// Layout: one wave (64 lanes) per node row; lanes split as 4 groups x 16.
// group g walks list entries j+g (4 gathers in flight); lane l covers float4
// features [4l..4l+3]. Butterfly shfl_xor(16/32) folds the 4 groups.

// y = 0.25*h + 0.75*(D^-1/2 (A+I) D^-1/2) xk ;  XB = x_bar = y - 0.25*U_old
// (FIRST: U_old == 0, skip the read; XB = y)
template <int FIRST>
__global__ __launch_bounds__(256) void adj_kernel(
    const float* __restrict__ Xk, const float* __restrict__ H,
    const float* __restrict__ U, const float* __restrict__ dis,
    const int* __restrict__ pA, const int* __restrict__ adjc,
    float* __restrict__ XB) {
  int w = (int)((blockIdx.x * 256u + threadIdx.x) >> 6);
  if (w >= NN) return;
  int lane = threadIdx.x & 63;
  int g = lane >> 4, l = lane & 15;
  const float4* X4 = (const float4*)Xk;
  float ax = 0.f, ay = 0.f, az = 0.f, aw = 0.f;
  int jb = pA[w], je = pA[w + 1];
  for (int j = jb + g; j < je; j += 4) {
    int col = adjc[j];
    float dc = dis[col];
    float4 xv = X4[col * 16 + l];
    ax = fmaf(dc, xv.x, ax);
    ay = fmaf(dc, xv.y, ay);
    az = fmaf(dc, xv.z, az);
    aw = fmaf(dc, xv.w, aw);
  }
  ax += __shfl_xor(ax, 16, 64); ay += __shfl_xor(ay, 16, 64);
  az += __shfl_xor(az, 16, 64); aw += __shfl_xor(aw, 16, 64);
  ax += __shfl_xor(ax, 32, 64); ay += __shfl_xor(ay, 32, 64);
  az += __shfl_xor(az, 32, 64); aw += __shfl_xor(aw, 32, 64);
  if (g == 0) {
    float di = dis[w];
    int idx = w * 16 + l;
    float4 xs = X4[idx];
    float4 h4 = ((const float4*)H)[idx];
    float4 y4;
    y4.x = 0.25f * h4.x + 0.75f * di * fmaf(di, xs.x, ax);
    y4.y = 0.25f * h4.y + 0.75f * di * fmaf(di, xs.y, ay);
    y4.z = 0.25f * h4.z + 0.75f * di * fmaf(di, xs.z, az);
    y4.w = 0.25f * h4.w + 0.75f * di * fmaf(di, xs.w, aw);
    float4 xb;
    if (FIRST) {
      xb = y4;
    } else {
      float4 u4 = ((const float4*)U)[idx];
      xb.x = y4.x - 0.25f * u4.x;
      xb.y = y4.y - 0.25f * u4.y;
      xb.z = y4.z - 0.25f * u4.z;
      xb.w = y4.w - 0.25f * u4.w;
    }
    ((float4*)XB)[idx] = xb;
  }
}

// z <- proj_L21( z + 2*(a*xb[r] - b*xb[c]) ), in place. Wave = 4 edge rows.
template <int FIRST>
__global__ __launch_bounds__(256) void zstep_kernel(
    float* __restrict__ Z, const float* __restrict__ XB,
    const float* __restrict__ dis,
    const int* __restrict__ src, const int* __restrict__ dst) {
  int w = (int)((blockIdx.x * 256u + threadIdx.x) >> 6);
  int lane = threadIdx.x & 63;
  int g = lane >> 4, l = lane & 15;
  int e = w * 4 + g;
  if (e >= NE) return;
  int s = src[e], d = dst[e];
  int r = s > d ? s : d;
  int c = s > d ? d : s;
  float a = dis[r], b = dis[c];
  const float4* X4 = (const float4*)XB;
  float4* Z4 = (float4*)Z;
  int zi = e * 16 + l;
  float4 xr = X4[r * 16 + l];
  float4 xc = X4[c * 16 + l];
  float zx, zy, zz, zw;
  if (FIRST) {
    zx = zy = zz = zw = 0.f;   // z0 = 0 (never read poisoned ws)
  } else {
    float4 z = Z4[zi];
    zx = z.x; zy = z.y; zz = z.z; zw = z.w;
  }
  zx += 2.0f * (a * xr.x - b * xc.x);
  zy += 2.0f * (a * xr.y - b * xc.y);
  zz += 2.0f * (a * xr.z - b * xc.z);
  zw += 2.0f * (a * xr.w - b * xc.w);
  float ss = zx * zx + zy * zy + zz * zz + zw * zw;
  ss += __shfl_xor(ss, 1, 64);
  ss += __shfl_xor(ss, 2, 64);
  ss += __shfl_xor(ss, 4, 64);
  ss += __shfl_xor(ss, 8, 64);   // 16-lane group sum (stays inside group)
  float rn = sqrtf(ss);
  float sc = (rn > LAM) ? (LAM / rn) : 1.0f;  // rn==0 -> z row already all-zero
  float4 o;
  o.x = sc * zx; o.y = sc * zy; o.z = sc * zz; o.w = sc * zw;
  Z4[zi] = o;
}

// u_new = dis_i * (sum_{r=i} z_e - sum_{c=i} z_e);
// y = XB + 0.25*U_old (reconstructed); Xout = y - 0.25*u_new; U <- u_new.
template <int FIRST>
__global__ __launch_bounds__(256) void incT_kernel(
    const float* __restrict__ Z, const float* __restrict__ XB,
    const float* __restrict__ dis,
    const int* __restrict__ pR, const int* __restrict__ reid,
    const int* __restrict__ pC, const int* __restrict__ ceid,
    float* __restrict__ U, float* __restrict__ Xout) {
  int w = (int)((blockIdx.x * 256u + threadIdx.x) >> 6);
  if (w >= NN) return;
  int lane = threadIdx.x & 63;
  int g = lane >> 4, l = lane & 15;
  const float4* Z4 = (const float4*)Z;
  float ax = 0.f, ay = 0.f, az = 0.f, aw = 0.f;
  int jb = pR[w], je = pR[w + 1];
  for (int j = jb + g; j < je; j += 4) {
    int e = reid[j];
    float4 z = Z4[e * 16 + l];
    ax += z.x; ay += z.y; az += z.z; aw += z.w;
  }
  jb = pC[w]; je = pC[w + 1];
  for (int j = jb + g; j < je; j += 4) {
    int e = ceid[j];
    float4 z = Z4[e * 16 + l];
    ax -= z.x; ay -= z.y; az -= z.z; aw -= z.w;
  }
  ax += __shfl_xor(ax, 16, 64); ay += __shfl_xor(ay, 16, 64);
  az += __shfl_xor(az, 16, 64); aw += __shfl_xor(aw, 16, 64);
  ax += __shfl_xor(ax, 32, 64); ay += __shfl_xor(ay, 32, 64);
  az += __shfl_xor(az, 32, 64); aw += __shfl_xor(aw, 32, 64);
  if (g == 0) {
    float di = dis[w];
    int idx = w * 16 + l;
    float4 u;
    u.x = di * ax; u.y = di * ay; u.z = di * az; u.w = di * aw;
    float4 xb = ((const float4*)XB)[idx];
    float4 y4;
    if (FIRST) {
      y4 = xb;  // U_old == 0
    } else {
      float4 uo = ((const float4*)U)[idx];
      y4.x = xb.x + 0.25f * uo.x;
      y4.y = xb.y + 0.25f * uo.y;
      y4.z = xb.z + 0.25f * uo.z;
      y4.w = xb.w + 0.25f * uo.w;
    }
    ((float4*)U)[idx] = u;
    float4 o;
    o.x = y4.x - 0.25f * u.x;
    o.y = y4.y - 0.25f * u.y;
    o.z = y4.z - 0.25f * u.z;
    o.w = y4.w - 0.25f * u.w;
    ((float4*)Xout)[idx] = o;
  }
}

// ---------------- launch ----------------

extern "C" void kernel_launch(void* const* d_in, const int* in_sizes, int n_in,
                              void* d_out, int out_size, void* d_ws, size_t ws_size,
                              hipStream_t stream) {
  const float* x  = (const float*)d_in[0];
  const int* esrc = (const int*)d_in[1];
  const int* edst = (const int*)d_in[2];
  float* out = (float*)d_out;

  char* base = (char*)d_ws;
  size_t off = 0;
  auto carve = [&](size_t bytes) -> void* {
    void* p = base + off;
    off += (bytes + 255) & ~(size_t)255;
    return p;
  };
  float* Z   = (float*)carve((size_t)NE * 64 * 4);   // 204.8 MB, carry state z
  float* XK  = (float*)carve((size_t)NN * 64 * 4);   // current xk
  float* XB  = (float*)carve((size_t)NN * 64 * 4);   // x_bar
  float* U   = (float*)carve((size_t)NN * 64 * 4);   // incT(z), reused next step
  float* dis = (float*)carve((size_t)NN * 4);
  int* cA = (int*)carve((size_t)NN * 4);
  int* cR = (int*)carve((size_t)NN * 4);
  int* cC = (int*)carve((size_t)NN * 4);
  int* pA = (int*)carve((size_t)(NN + 1) * 4);
  int* pR = (int*)carve((size_t)(NN + 1) * 4);
  int* pC = (int*)carve((size_t)(NN + 1) * 4);
  int* uA = (int*)carve((size_t)NN * 4);
  int* uR = (int*)carve((size_t)NN * 4);
  int* uC = (int*)carve((size_t)NN * 4);
  int* adjc = (int*)carve((size_t)2 * NE * 4);
  int* reid = (int*)carve((size_t)NE * 4);
  int* ceid = (int*)carve((size_t)NE * 4);
  (void)ws_size; (void)in_sizes; (void)n_in; (void)out_size;

  hipMemsetAsync(cA, 0, NN * 4, stream);
  hipMemsetAsync(cR, 0, NN * 4, stream);
  hipMemsetAsync(cC, 0, NN * 4, stream);

  count_kernel<<<(NE + 255) / 256, 256, 0, stream>>>(esrc, edst, cA, cR, cC);
  dis_kernel<<<(NN + 255) / 256, 256, 0, stream>>>(cA, dis);
  scan3_kernel<<<3, 1024, 0, stream>>>(cA, cR, cC, pA, pR, pC, uA, uR, uC);
  scatter_kernel<<<(NE + 255) / 256, 256, 0, stream>>>(esrc, edst, uA, uR, uC,
                                                       adjc, reid, ceid);

  const int nodeBlocks = NN * 64 / 256;      // 12500 (one wave per node, exact)
  const int edgeBlocks = (NE / 4) * 64 / 256; // 50000 (wave = 4 edges, exact)

  for (int k = 0; k < KS; ++k) {
    const float* xk = (k == 0) ? x : XK;
    if (k == 0)
      adj_kernel<1><<<nodeBlocks, 256, 0, stream>>>(xk, x, U, dis, pA, adjc, XB);
    else
      adj_kernel<0><<<nodeBlocks, 256, 0, stream>>>(xk, x, U, dis, pA, adjc, XB);

    if (k == 0)
      zstep_kernel<1><<<edgeBlocks, 256, 0, stream>>>(Z, XB, dis, esrc, edst);
    else
      zstep_kernel<0><<<edgeBlocks, 256, 0, stream>>>(Z, XB, dis, esrc, edst);

    float* xout = (k == KS - 1) ? out : XK;
    if (k == 0)
      incT_kernel<1><<<nodeBlocks, 256, 0, stream>>>(Z, XB, dis, pR, reid, pC,
                                                     ceid, U, xout);
    else
      incT_kernel<0><<<nodeBlocks, 256, 0, stream>>>(Z, XB, dis, pR, reid, pC,
                                                     ceid, U, xout);
  }
}

// Round 2
// 2113.736 us; speedup vs baseline: 1.3430x; 1.3430x over previous
//
#include <hip/hip_runtime.h>
#include <hip/hip_fp16.h>
#include <math.h>

// Problem constants (match reference)
constexpr int NN = 50000;    // nodes
constexpr int NE = 800000;   // undirected edges E0
constexpr int KS = 10;       // iterations
constexpr float LAM = 3.0f;  // lambda

// ---------------- precompute kernels ----------------

__global__ __launch_bounds__(256) void count_kernel(
    const int* __restrict__ src, const int* __restrict__ dst,
    int* __restrict__ cA) {
  int e = blockIdx.x * 256 + threadIdx.x;
  if (e >= NE) return;
  int s = src[e], d = dst[e];
  atomicAdd(&cA[s], 1);
  atomicAdd(&cA[d], 1);
}

__global__ __launch_bounds__(256) void dis_kernel(
    const int* __restrict__ cA, float* __restrict__ dis) {
  int i = blockIdx.x * 256 + threadIdx.x;
  if (i < NN) dis[i] = 1.0f / sqrtf((float)(cA[i] + 1)); // deg incl. self loop
}

// exclusive scan of counts -> ptr (N+1) and cursor copy (single block)
__global__ __launch_bounds__(1024) void scan_kernel(
    const int* __restrict__ cnt, int* __restrict__ ptr, int* __restrict__ cur) {
  __shared__ int part[1024];
  int t = threadIdx.x;
  const int per = (NN + 1023) / 1024;  // 49
  int s0 = t * per;
  int s1 = s0 + per; if (s1 > NN) s1 = NN;
  if (s0 > NN) s0 = NN;
  int s = 0;
  for (int i = s0; i < s1; ++i) s += cnt[i];
  part[t] = s;
  __syncthreads();
  for (int off = 1; off < 1024; off <<= 1) {
    int v = part[t];
    int a = (t >= off) ? part[t - off] : 0;
    __syncthreads();
    part[t] = v + a;
    __syncthreads();
  }
  int base = (t == 0) ? 0 : part[t - 1];
  for (int i = s0; i < s1; ++i) {
    int cv = cnt[i];
    ptr[i] = base;
    cur[i] = base;
    base += cv;
  }
  if (s1 == NN) ptr[NN] = base;  // trailing threads all write the total
}

// Combined incident-edge CSR: per node, int2 entries (other_endpoint,
// edge_id | SIGNBIT). SIGNBIT set iff this node is r = max(s,d) (the +1 side
// of the incidence row). Self edges (s==d) get exactly one + and one - entry.
__global__ __launch_bounds__(256) void scatter_kernel(
    const int* __restrict__ src, const int* __restrict__ dst,
    int* __restrict__ uA, int2* __restrict__ ents) {
  int e = blockIdx.x * 256 + threadIdx.x;
  if (e >= NE) return;
  int s = src[e], d = dst[e];
  int p = atomicAdd(&uA[s], 1);
  ents[p] = make_int2(d, e | ((s >= d) ? 0x80000000 : 0));
  p = atomicAdd(&uA[d], 1);
  ents[p] = make_int2(s, e | ((d > s) ? 0x80000000 : 0));
}

// ---------------- per-step kernels ----------------
// One wave (64 lanes) per node row; lanes split as 4 groups x 16.
// Group g walks list entries j+g (4 gathers in flight); lane l covers float4
// features [4l..4l+3]. Butterfly shfl_xor(16/32) folds the 4 groups.

// y = 0.25*h + 0.75*(D^-1/2 (A+I) D^-1/2) xk ;  XB = x_bar = y - 0.25*U_old
// (FIRST: U_old == 0 -> XB = y)
template <int FIRST>
__global__ __launch_bounds__(256) void adj_kernel(
    const float* __restrict__ Xk, const float* __restrict__ H,
    const float* __restrict__ U, const float* __restrict__ dis,
    const int* __restrict__ pA, const int2* __restrict__ ents,
    float* __restrict__ XB) {
  int w = (int)((blockIdx.x * 256u + threadIdx.x) >> 6);
  if (w >= NN) return;
  int lane = threadIdx.x & 63;
  int g = lane >> 4, l = lane & 15;
  const float4* X4 = (const float4*)Xk;
  float ax = 0.f, ay = 0.f, az = 0.f, aw = 0.f;
  int jb = pA[w], je = pA[w + 1];
  for (int j = jb + g; j < je; j += 4) {
    int col = ents[j].x;
    float dc = dis[col];
    float4 xv = X4[col * 16 + l];
    ax = fmaf(dc, xv.x, ax);
    ay = fmaf(dc, xv.y, ay);
    az = fmaf(dc, xv.z, az);
    aw = fmaf(dc, xv.w, aw);
  }
  ax += __shfl_xor(ax, 16, 64); ay += __shfl_xor(ay, 16, 64);
  az += __shfl_xor(az, 16, 64); aw += __shfl_xor(aw, 16, 64);
  ax += __shfl_xor(ax, 32, 64); ay += __shfl_xor(ay, 32, 64);
  az += __shfl_xor(az, 32, 64); aw += __shfl_xor(aw, 32, 64);
  if (g == 0) {
    float di = dis[w];
    int idx = w * 16 + l;
    float4 xs = X4[idx];
    float4 h4 = ((const float4*)H)[idx];
    float4 y4;
    y4.x = 0.25f * h4.x + 0.75f * di * fmaf(di, xs.x, ax);
    y4.y = 0.25f * h4.y + 0.75f * di * fmaf(di, xs.y, ay);
    y4.z = 0.25f * h4.z + 0.75f * di * fmaf(di, xs.z, az);
    y4.w = 0.25f * h4.w + 0.75f * di * fmaf(di, xs.w, aw);
    float4 xb;
    if (FIRST) {
      xb = y4;
    } else {
      float4 u4 = ((const float4*)U)[idx];
      xb.x = y4.x - 0.25f * u4.x;
      xb.y = y4.y - 0.25f * u4.y;
      xb.z = y4.z - 0.25f * u4.z;
      xb.w = y4.w - 0.25f * u4.w;
    }
    ((float4*)XB)[idx] = xb;
  }
}

// z <- proj_L21( z + 2*(a*xb[r] - b*xb[c]) ), in place, Z stored fp16.
// Wave = 4 edge rows.
template <int FIRST>
__global__ __launch_bounds__(256) void zstep_kernel(
    __half* __restrict__ Z, const float* __restrict__ XB,
    const float* __restrict__ dis,
    const int* __restrict__ src, const int* __restrict__ dst) {
  int w = (int)((blockIdx.x * 256u + threadIdx.x) >> 6);
  int lane = threadIdx.x & 63;
  int g = lane >> 4, l = lane & 15;
  int e = w * 4 + g;
  if (e >= NE) return;
  int s = src[e], d = dst[e];
  int r = s > d ? s : d;
  int c = s > d ? d : s;
  float a = dis[r], b = dis[c];
  const float4* X4 = (const float4*)XB;
  uint2* Z2 = (uint2*)Z;
  int zi = e * 16 + l;
  float4 xr = X4[r * 16 + l];
  float4 xc = X4[c * 16 + l];
  float zx, zy, zz, zw;
  if (FIRST) {
    zx = zy = zz = zw = 0.f;   // z0 = 0 (never read poisoned ws)
  } else {
    uint2 zu = Z2[zi];
    float2 f0 = __half22float2(*(const __half2*)&zu.x);
    float2 f1 = __half22float2(*(const __half2*)&zu.y);
    zx = f0.x; zy = f0.y; zz = f1.x; zw = f1.y;
  }
  zx += 2.0f * (a * xr.x - b * xc.x);
  zy += 2.0f * (a * xr.y - b * xc.y);
  zz += 2.0f * (a * xr.z - b * xc.z);
  zw += 2.0f * (a * xr.w - b * xc.w);
  float ss = zx * zx + zy * zy + zz * zz + zw * zw;
  ss += __shfl_xor(ss, 1, 64);
  ss += __shfl_xor(ss, 2, 64);
  ss += __shfl_xor(ss, 4, 64);
  ss += __shfl_xor(ss, 8, 64);   // 16-lane group sum (stays inside group)
  float rn = sqrtf(ss);
  float sc = (rn > LAM) ? (LAM / rn) : 1.0f;
  __half2 o0 = __floats2half2_rn(sc * zx, sc * zy);
  __half2 o1 = __floats2half2_rn(sc * zz, sc * zw);
  uint2 outu;
  outu.x = *(const unsigned*)&o0;
  outu.y = *(const unsigned*)&o1;
  Z2[zi] = outu;
}

// u_new = dis_i * sum_{e incident i} sign_e * z_e ;
// y = XB + 0.25*U_old (reconstructed); Xout = y - 0.25*u_new; U <- u_new.
template <int FIRST, int LAST>
__global__ __launch_bounds__(256) void incT_kernel(
    const __half* __restrict__ Z, const float* __restrict__ XB,
    const float* __restrict__ dis,
    const int* __restrict__ pA, const int2* __restrict__ ents,
    float* __restrict__ U, float* __restrict__ Xout) {
  int w = (int)((blockIdx.x * 256u + threadIdx.x) >> 6);
  if (w >= NN) return;
  int lane = threadIdx.x & 63;
  int g = lane >> 4, l = lane & 15;
  const uint2* Z2 = (const uint2*)Z;
  float ax = 0.f, ay = 0.f, az = 0.f, aw = 0.f;
  int jb = pA[w], je = pA[w + 1];
  for (int j = jb + g; j < je; j += 4) {
    int raw = ents[j].y;
    int e = raw & 0x7FFFFFFF;
    float sgn = (raw < 0) ? 1.0f : -1.0f;  // sign bit set => +1 (r side)
    uint2 zu = Z2[e * 16 + l];
    float2 f0 = __half22float2(*(const __half2*)&zu.x);
    float2 f1 = __half22float2(*(const __half2*)&zu.y);
    ax = fmaf(sgn, f0.x, ax);
    ay = fmaf(sgn, f0.y, ay);
    az = fmaf(sgn, f1.x, az);
    aw = fmaf(sgn, f1.y, aw);
  }
  ax += __shfl_xor(ax, 16, 64); ay += __shfl_xor(ay, 16, 64);
  az += __shfl_xor(az, 16, 64); aw += __shfl_xor(aw, 16, 64);
  ax += __shfl_xor(ax, 32, 64); ay += __shfl_xor(ay, 32, 64);
  az += __shfl_xor(az, 32, 64); aw += __shfl_xor(aw, 32, 64);
  if (g == 0) {
    float di = dis[w];
    int idx = w * 16 + l;
    float4 u;
    u.x = di * ax; u.y = di * ay; u.z = di * az; u.w = di * aw;
    float4 xb = ((const float4*)XB)[idx];
    float4 y4;
    if (FIRST) {
      y4 = xb;  // U_old == 0
    } else {
      float4 uo = ((const float4*)U)[idx];
      y4.x = xb.x + 0.25f * uo.x;
      y4.y = xb.y + 0.25f * uo.y;
      y4.z = xb.z + 0.25f * uo.z;
      y4.w = xb.w + 0.25f * uo.w;
    }
    if (!LAST) ((float4*)U)[idx] = u;  // dead after final step
    float4 o;
    o.x = y4.x - 0.25f * u.x;
    o.y = y4.y - 0.25f * u.y;
    o.z = y4.z - 0.25f * u.z;
    o.w = y4.w - 0.25f * u.w;
    ((float4*)Xout)[idx] = o;
  }
}

// ---------------- launch ----------------

extern "C" void kernel_launch(void* const* d_in, const int* in_sizes, int n_in,
                              void* d_out, int out_size, void* d_ws, size_t ws_size,
                              hipStream_t stream) {
  const float* x  = (const float*)d_in[0];
  const int* esrc = (const int*)d_in[1];
  const int* edst = (const int*)d_in[2];
  float* out = (float*)d_out;

  char* base = (char*)d_ws;
  size_t off = 0;
  auto carve = [&](size_t bytes) -> void* {
    void* p = base + off;
    off += (bytes + 255) & ~(size_t)255;
    return p;
  };
  __half* Z  = (__half*)carve((size_t)NE * 64 * 2);  // 102.4 MB, carry state z
  float* XK  = (float*)carve((size_t)NN * 64 * 4);   // current xk
  float* XB  = (float*)carve((size_t)NN * 64 * 4);   // x_bar
  float* U   = (float*)carve((size_t)NN * 64 * 4);   // incT(z), reused next step
  float* dis = (float*)carve((size_t)NN * 4);
  int* cA = (int*)carve((size_t)NN * 4);
  int* pA = (int*)carve((size_t)(NN + 1) * 4);
  int* uA = (int*)carve((size_t)NN * 4);
  int2* ents = (int2*)carve((size_t)2 * NE * 8);     // 12.8 MB combined CSR
  (void)ws_size; (void)in_sizes; (void)n_in; (void)out_size;

  hipMemsetAsync(cA, 0, NN * 4, stream);

  count_kernel<<<(NE + 255) / 256, 256, 0, stream>>>(esrc, edst, cA);
  dis_kernel<<<(NN + 255) / 256, 256, 0, stream>>>(cA, dis);
  scan_kernel<<<1, 1024, 0, stream>>>(cA, pA, uA);
  scatter_kernel<<<(NE + 255) / 256, 256, 0, stream>>>(esrc, edst, uA, ents);

  const int nodeBlocks = NN * 64 / 256;       // 12500 (one wave/node, exact)
  const int edgeBlocks = (NE / 4) * 64 / 256; // 50000 (wave = 4 edges, exact)

  for (int k = 0; k < KS; ++k) {
    const float* xk = (k == 0) ? x : XK;
    if (k == 0)
      adj_kernel<1><<<nodeBlocks, 256, 0, stream>>>(xk, x, U, dis, pA, ents, XB);
    else
      adj_kernel<0><<<nodeBlocks, 256, 0, stream>>>(xk, x, U, dis, pA, ents, XB);

    if (k == 0)
      zstep_kernel<1><<<edgeBlocks, 256, 0, stream>>>(Z, XB, dis, esrc, edst);
    else
      zstep_kernel<0><<<edgeBlocks, 256, 0, stream>>>(Z, XB, dis, esrc, edst);

    float* xout = (k == KS - 1) ? out : XK;
    if (k == 0)
      incT_kernel<1, 0><<<nodeBlocks, 256, 0, stream>>>(Z, XB, dis, pA, ents, U, xout);
    else if (k == KS - 1)
      incT_kernel<0, 1><<<nodeBlocks, 256, 0, stream>>>(Z, XB, dis, pA, ents, U, xout);
    else
      incT_kernel<0, 0><<<nodeBlocks, 256, 0, stream>>>(Z, XB, dis, pA, ents, U, xout);
  }
}